// Round 4
// baseline (280.321 us; speedup 1.0000x reference)
//
#include <hip/hip_runtime.h>

#define BATCH 64
#define TLEN  512
#define HDIM  768
#define LTAGS 9

// Workspace layout (bytes)
#define WS_LOGD 0                        // f64 [32768][9] = 2359296
#define WS_LOSS 2359296                  // f64 [64]

// ---------------------------------------------------------------------------
// Kernel A: logits = hidden @ W^T + b.  f32 dot4 segments accumulated in f64.
// ---------------------------------------------------------------------------
__global__ __launch_bounds__(256) void logits_kernel(
    const float* __restrict__ hidden, const float* __restrict__ W,
    const float* __restrict__ bvec, double* __restrict__ logitsD)
{
    __shared__ float sW[LTAGS * HDIM];
    __shared__ float sb[LTAGS];
    const int tid = threadIdx.x;
    for (int i = tid; i < LTAGS * HDIM; i += 256) sW[i] = W[i];
    if (tid < LTAGS) sb[tid] = bvec[tid];
    __syncthreads();

    const int lane = tid & 63;
    const int wave = tid >> 6;
    const int sub  = lane & 7;
    const int rg   = lane >> 3;

    const int rowBase = blockIdx.x * 64 + wave * 16;
    const int r0 = rowBase + rg;
    const int r1 = rowBase + rg + 8;
    const float* h0p = hidden + (size_t)r0 * HDIM;
    const float* h1p = hidden + (size_t)r1 * HDIM;

    double acc0[LTAGS], acc1[LTAGS];
    #pragma unroll
    for (int l = 0; l < LTAGS; ++l) { acc0[l] = 0.0; acc1[l] = 0.0; }

    #pragma unroll 2
    for (int i = 0; i < 24; ++i) {
        const int off = i * 32 + sub * 4;
        const float4 h0 = *(const float4*)(h0p + off);
        const float4 h1 = *(const float4*)(h1p + off);
        #pragma unroll
        for (int l = 0; l < LTAGS; ++l) {
            const float4 w = *(const float4*)&sW[l * HDIM + off];
            float d0 = h0.x * w.x;
            d0 = fmaf(h0.y, w.y, d0); d0 = fmaf(h0.z, w.z, d0); d0 = fmaf(h0.w, w.w, d0);
            float d1 = h1.x * w.x;
            d1 = fmaf(h1.y, w.y, d1); d1 = fmaf(h1.z, w.z, d1); d1 = fmaf(h1.w, w.w, d1);
            acc0[l] += (double)d0;
            acc1[l] += (double)d1;
        }
    }
    #pragma unroll
    for (int l = 0; l < LTAGS; ++l) {
        double v0 = acc0[l], v1 = acc1[l];
        #pragma unroll
        for (int off = 4; off > 0; off >>= 1) {
            v0 += __shfl_down(v0, off);
            v1 += __shfl_down(v1, off);
        }
        acc0[l] = v0; acc1[l] = v1;
    }
    if (sub == 0) {
        #pragma unroll
        for (int l = 0; l < LTAGS; ++l) {
            logitsD[(size_t)r0 * LTAGS + l] = acc0[l] + (double)sb[l];
            logitsD[(size_t)r1 * LTAGS + l] = acc1[l] + (double)sb[l];
        }
    }
}

// ---------------------------------------------------------------------------
// Kernel B (fused CRF): one block (576 thr = 9 waves) per batch.
//  P0: stage trans/masks, numerator (f64)
//  P1: Viterbi chunk mats (64 chunks x 8 steps, f64 max-plus) -> LDS
//  P2: wave0 Viterbi boundary scan  ||  waves1-5 alpha chunk mats (f32) -> LDS
//  P3: wave0 replay+backpointers+suffix-composition  ||  wave1 alpha scan
//  P4: chunk-parallel prediction expansion; loss parts
// f64 Viterbi arithmetic identical to round-3 (bit-exact decisions).
// ---------------------------------------------------------------------------
__global__ __launch_bounds__(576) void crf_fused(
    const float* __restrict__ trans, const int* __restrict__ labels,
    const int* __restrict__ att, const double* __restrict__ logitsD,
    double* __restrict__ wsLoss, float* __restrict__ out)
{
    __shared__ __align__(16) double sVM[64 * 81];     // 41472 B
    __shared__ __align__(16) float  sAM[32 * 81];     // 10368 B
    __shared__ double sVstart[65 * LTAGS];            // 4680 B
    __shared__ unsigned long long sBPp[513];          // 4104 B
    __shared__ double sT64[81];
    __shared__ float  sE32[81];
    __shared__ unsigned char sMk[513];
    __shared__ int sTagB[65];
    __shared__ double sRedN[9];
    __shared__ double sNum, sDen;
    __shared__ int sLast;

    const int b = blockIdx.x, tid = threadIdx.x;
    const int wave = tid >> 6, lane = tid & 63;
    const unsigned long long IDMAP = 0x876543210ull;

    const int* lab = labels + b * TLEN;
    const int* am  = att + b * TLEN;
    const double* gLD = logitsD + (size_t)b * TLEN * LTAGS;

    // ---- P0: stage + numerator ----
    if (tid < 81) { float tv = trans[tid]; sT64[tid] = (double)tv; sE32[tid] = __expf(tv); }
    if (tid < TLEN) {
        int lv = lab[tid], av = am[tid];
        sMk[tid] = (av != 0 && lv != -100) ? 1 : 0;
    }
    if (tid == 0) sMk[TLEN] = 0;

    double part = 0.0;
    if (tid < TLEN) {
        const int t = tid;
        int lv = lab[t], av = am[t];
        bool mkc = (av != 0) && (lv != -100);
        int tg = (lv == -100) ? 0 : lv;
        if (mkc) part += gLD[(size_t)t * LTAGS + tg];
        if (t < TLEN - 1) {
            int lv2 = lab[t + 1], av2 = am[t + 1];
            bool mk2 = (av2 != 0) && (lv2 != -100);
            int tg2 = (lv2 == -100) ? 0 : lv2;
            if (mk2) part += (double)trans[tg * LTAGS + tg2];
        }
    }
    #pragma unroll
    for (int off = 32; off > 0; off >>= 1) part += __shfl_down(part, off);
    if (lane == 0) sRedN[wave] = part;
    __syncthreads();
    if (tid == 0) {
        double s = 0.0;
        for (int w = 0; w < 9; ++w) s += sRedN[w];
        sNum = s;
    }

    // ---- P1: Viterbi chunk matrices (all 576 threads) ----
    {
        const int c = tid / 9, i = tid - 9 * c;
        double M[LTAGS];
        #pragma unroll
        for (int j = 0; j < LTAGS; ++j) M[j] = (i == j) ? 0.0 : -1e300;

        const double* lrow = gLD + (size_t)(c * 8 + 1) * LTAGS;
        const int t0 = c * 8 + 1;

        double lg[LTAGS], lgN[LTAGS];
        #pragma unroll
        for (int j = 0; j < LTAGS; ++j) lg[j] = lrow[j];
        bool mk = (sMk[t0] != 0);

        for (int s = 0; s < 8; ++s) {
            bool mkN = false;
            const int tn = t0 + s + 1;
            if (s < 7 && tn <= TLEN - 1) {
                const double* ln = lrow + (s + 1) * LTAGS;
                #pragma unroll
                for (int j = 0; j < LTAGS; ++j) lgN[j] = ln[j];
                mkN = (sMk[tn] != 0);
            }
            double nw[LTAGS];
            #pragma unroll
            for (int j = 0; j < LTAGS; ++j) {
                double bst = M[0] + sT64[j];
                #pragma unroll
                for (int k = 1; k < LTAGS; ++k) {
                    double cnd = M[k] + sT64[k * LTAGS + j];
                    bst = fmax(bst, cnd);
                }
                nw[j] = bst + lg[j];
            }
            #pragma unroll
            for (int j = 0; j < LTAGS; ++j) { M[j] = mk ? nw[j] : M[j]; lg[j] = lgN[j]; }
            mk = mkN;
        }
        #pragma unroll
        for (int j = 0; j < LTAGS; ++j) sVM[c * 81 + i * LTAGS + j] = M[j];
    }
    __syncthreads();

    // ---- P2: wave0 Viterbi boundary scan || waves1-5 alpha chunk mats ----
    if (wave == 0) {
        const int j = (lane < LTAGS) ? lane : (LTAGS - 1);
        double v = gLD[j];
        double Mc[LTAGS], Mn[LTAGS];
        #pragma unroll
        for (int i = 0; i < LTAGS; ++i) Mc[i] = sVM[i * LTAGS + j];
        for (int c = 0; c < 64; ++c) {
            if (c < 63) {
                #pragma unroll
                for (int i = 0; i < LTAGS; ++i) Mn[i] = sVM[(c + 1) * 81 + i * LTAGS + j];
            }
            if (lane < LTAGS) sVstart[c * LTAGS + j] = v;
            double g[LTAGS];
            #pragma unroll
            for (int i = 0; i < LTAGS; ++i) g[i] = __shfl(v, i);
            double bst = g[0] + Mc[0];
            #pragma unroll
            for (int i = 1; i < LTAGS; ++i) bst = fmax(bst, g[i] + Mc[i]);
            v = bst;
            if (c < 63) {
                #pragma unroll
                for (int i = 0; i < LTAGS; ++i) Mc[i] = Mn[i];
            }
        }
        if (lane < LTAGS) sVstart[64 * LTAGS + j] = v;
        double g[LTAGS];
        #pragma unroll
        for (int i = 0; i < LTAGS; ++i) g[i] = __shfl(v, i);
        if (lane == 0) {
            int bi = 0; double bv = g[0];
            #pragma unroll
            for (int i = 1; i < LTAGS; ++i) if (g[i] > bv) { bv = g[i]; bi = i; }
            sLast = bi;
        }
    } else if (tid >= 64 && tid < 352) {
        // alpha chunk matrices: 32 chunks x 16 steps, f32 log-plus
        const int idx = tid - 64;
        const int c = idx / 9, i = idx - 9 * c;
        float M[LTAGS];
        #pragma unroll
        for (int j = 0; j < LTAGS; ++j) M[j] = (i == j) ? 0.f : -1e30f;

        const double* lrow = gLD + (size_t)(c * 16 + 1) * LTAGS;
        const int t0 = c * 16 + 1;

        float lg[LTAGS], lgN[LTAGS];
        #pragma unroll
        for (int j = 0; j < LTAGS; ++j) lg[j] = (float)lrow[j];
        bool mk = (sMk[t0] != 0);

        for (int s = 0; s < 16; ++s) {
            bool mkN = false;
            const int tn = t0 + s + 1;
            if (s < 15 && tn <= TLEN - 1) {
                const double* ln = lrow + (s + 1) * LTAGS;
                #pragma unroll
                for (int j = 0; j < LTAGS; ++j) lgN[j] = (float)ln[j];
                mkN = (sMk[tn] != 0);
            }
            float m = M[0];
            #pragma unroll
            for (int k = 1; k < LTAGS; ++k) m = fmaxf(m, M[k]);
            float P[LTAGS];
            #pragma unroll
            for (int k = 0; k < LTAGS; ++k) P[k] = __expf(M[k] - m);
            float nw[LTAGS];
            #pragma unroll
            for (int j = 0; j < LTAGS; ++j) {
                float sacc = P[0] * sE32[j];
                #pragma unroll
                for (int k = 1; k < LTAGS; ++k) sacc = fmaf(P[k], sE32[k * LTAGS + j], sacc);
                nw[j] = m + __logf(sacc) + lg[j];
            }
            #pragma unroll
            for (int j = 0; j < LTAGS; ++j) { M[j] = mk ? nw[j] : M[j]; lg[j] = lgN[j]; }
            mk = mkN;
        }
        #pragma unroll
        for (int j = 0; j < LTAGS; ++j) sAM[c * 81 + i * LTAGS + j] = M[j];
    }
    __syncthreads();

    // ---- P3: wave0 replay+compose || wave1 alpha boundary scan ----
    unsigned long long S = IDMAP;
    if (wave == 0) {
        const int c = tid;
        double v[LTAGS];
        #pragma unroll
        for (int j = 0; j < LTAGS; ++j) v[j] = sVstart[c * LTAGS + j];
        const double* lrow = gLD + (size_t)(c * 8 + 1) * LTAGS;
        double lg[LTAGS], lgN[LTAGS];
        #pragma unroll
        for (int j = 0; j < LTAGS; ++j) lg[j] = lrow[j];

        for (int s = 0; s < 8; ++s) {
            const int t = c * 8 + 1 + s;
            if (s < 7 && t + 1 <= TLEN - 1) {
                const double* ln = lrow + (s + 1) * LTAGS;
                #pragma unroll
                for (int j = 0; j < LTAGS; ++j) lgN[j] = ln[j];
            }
            const bool mk = (sMk[t] != 0);
            unsigned long long pk = 0;
            double nv[LTAGS];
            #pragma unroll
            for (int j = 0; j < LTAGS; ++j) {
                double bst = v[0] + sT64[j];
                int bi = 0;
                #pragma unroll
                for (int k = 1; k < LTAGS; ++k) {
                    double cnd = v[k] + sT64[k * LTAGS + j];
                    bool gt = cnd > bst;
                    bst = gt ? cnd : bst;
                    bi  = gt ? k : bi;
                }
                nv[j] = bst + lg[j];
                pk |= ((unsigned long long)bi) << (4 * j);
            }
            pk = mk ? pk : IDMAP;
            sBPp[t] = pk;
            #pragma unroll
            for (int j = 0; j < LTAGS; ++j) { v[j] = mk ? nv[j] : v[j]; lg[j] = lgN[j]; }
        }
        unsigned long long G = IDMAP;
        for (int s = 7; s >= 0; --s) {
            const unsigned long long bp = sBPp[c * 8 + 1 + s];
            unsigned long long ng = 0;
            #pragma unroll
            for (int j = 0; j < LTAGS; ++j) {
                int gj = (int)((G >> (4 * j)) & 15);
                int f  = (int)((bp >> (4 * gj)) & 15);
                ng |= ((unsigned long long)f) << (4 * j);
            }
            G = ng;
        }
        S = G;
    } else if (wave == 1) {
        const int j = (lane < LTAGS) ? lane : (LTAGS - 1);
        float v = (float)gLD[j];
        float Mc[LTAGS], Mn[LTAGS];
        #pragma unroll
        for (int i = 0; i < LTAGS; ++i) Mc[i] = sAM[i * LTAGS + j];
        for (int c = 0; c < 32; ++c) {
            if (c < 31) {
                #pragma unroll
                for (int i = 0; i < LTAGS; ++i) Mn[i] = sAM[(c + 1) * 81 + i * LTAGS + j];
            }
            float g[LTAGS];
            #pragma unroll
            for (int i = 0; i < LTAGS; ++i) g[i] = __shfl(v, i);
            float a[LTAGS];
            #pragma unroll
            for (int i = 0; i < LTAGS; ++i) a[i] = g[i] + Mc[i];
            float m = a[0];
            #pragma unroll
            for (int i = 1; i < LTAGS; ++i) m = fmaxf(m, a[i]);
            float sacc = 0.f;
            #pragma unroll
            for (int i = 0; i < LTAGS; ++i) sacc += __expf(a[i] - m);
            v = m + __logf(sacc);
            if (c < 31) {
                #pragma unroll
                for (int i = 0; i < LTAGS; ++i) Mc[i] = Mn[i];
            }
        }
        float g[LTAGS];
        #pragma unroll
        for (int i = 0; i < LTAGS; ++i) g[i] = __shfl(v, i);
        if (lane == 0) {
            float m = g[0];
            #pragma unroll
            for (int i = 1; i < LTAGS; ++i) m = fmaxf(m, g[i]);
            float sacc = 0.f;
            #pragma unroll
            for (int i = 0; i < LTAGS; ++i) sacc += __expf(g[i] - m);
            sDen = (double)(m + __logf(sacc));
        }
    }

    // ---- suffix composition scan (within wave0) ----
    #pragma unroll
    for (int d = 1; d < 64; d <<= 1) {
        unsigned long long Sn = __shfl_down(S, d);
        if (wave == 0 && lane + d < 64) {
            unsigned long long R = 0;
            #pragma unroll
            for (int x = 0; x < LTAGS; ++x) {
                int y = (int)((Sn >> (4 * x)) & 15);
                int z = (int)((S >> (4 * y)) & 15);
                R |= ((unsigned long long)z) << (4 * x);
            }
            S = R;
        }
    }

    // ---- P4: boundary tags + expansion (wave0; same-wave LDS ordering) ----
    if (wave == 0) {
        const int lt = sLast;
        sTagB[tid] = (int)((S >> (4 * lt)) & 15);
        if (tid == 0) sTagB[64] = lt;

        const int c = tid;
        int cur = sTagB[c + 1];
        float* po = out + 1 + b * TLEN;
        for (int s = 8; s >= 1; --s) {
            const int t = c * 8 + s;
            if (t < TLEN) {
                int nxt = (int)((sBPp[t] >> (4 * cur)) & 15);
                po[t] = sMk[t - 1] ? (float)nxt : -100.f;
                cur = nxt;
            }
        }
    }
    __syncthreads();
    if (tid == 0) {
        out[1 + b * TLEN] = -100.f;
        wsLoss[b] = sDen - sNum;
    }
}

// ---------------------------------------------------------------------------
// Kernel C: loss = sum_b (den_b - num_b)
// ---------------------------------------------------------------------------
__global__ __launch_bounds__(64) void loss_kernel(
    const double* __restrict__ wsLoss, float* __restrict__ out)
{
    double v = wsLoss[threadIdx.x];
    #pragma unroll
    for (int off = 32; off > 0; off >>= 1) v += __shfl_down(v, off);
    if (threadIdx.x == 0) out[0] = (float)v;
}

extern "C" void kernel_launch(void* const* d_in, const int* in_sizes, int n_in,
                              void* d_out, int out_size, void* d_ws, size_t ws_size,
                              hipStream_t stream)
{
    const float* hidden = (const float*)d_in[0];
    const float* W      = (const float*)d_in[1];
    const float* bvec   = (const float*)d_in[2];
    const float* trans  = (const float*)d_in[3];
    const int*   labels = (const int*)d_in[4];
    const int*   att    = (const int*)d_in[5];
    float* out = (float*)d_out;

    char* ws = (char*)d_ws;
    double* logitsD = (double*)(ws + WS_LOGD);
    double* wsLoss  = (double*)(ws + WS_LOSS);

    logits_kernel<<<512, 256, 0, stream>>>(hidden, W, bvec, logitsD);
    crf_fused<<<BATCH, 576, 0, stream>>>(trans, labels, att, logitsD, wsLoss, out);
    loss_kernel<<<1, 64, 0, stream>>>(wsLoss, out);
}

// Round 5
// 219.248 us; speedup vs baseline: 1.2786x; 1.2786x over previous
//
#include <hip/hip_runtime.h>

#define BATCH 64
#define TLEN  512
#define HDIM  768
#define LTAGS 9

// Workspace layout (bytes)
#define WS_LOGD 0                        // f64 [32768][9] = 2359296
#define WS_VM   2359296                  // f64 [64][64][9][9] = 2654208
#define WS_AM   5013504                  // f32 [64][32][9][9] = 663552
#define WS_NUM  5677056                  // f64 [64]

// ---------------------------------------------------------------------------
// Kernel A: logits = hidden @ W^T + b.  f32 dot4 segments accumulated in f64.
// (identical numerics to rounds 2-4; validated absmax 0.0)
// ---------------------------------------------------------------------------
__global__ __launch_bounds__(256) void logits_kernel(
    const float* __restrict__ hidden, const float* __restrict__ W,
    const float* __restrict__ bvec, double* __restrict__ logitsD)
{
    __shared__ float sW[LTAGS * HDIM];
    __shared__ float sb[LTAGS];
    const int tid = threadIdx.x;
    for (int i = tid; i < LTAGS * HDIM; i += 256) sW[i] = W[i];
    if (tid < LTAGS) sb[tid] = bvec[tid];
    __syncthreads();

    const int lane = tid & 63;
    const int wave = tid >> 6;
    const int sub  = lane & 7;
    const int rg   = lane >> 3;

    const int rowBase = blockIdx.x * 64 + wave * 16;
    const int r0 = rowBase + rg;
    const int r1 = rowBase + rg + 8;
    const float* h0p = hidden + (size_t)r0 * HDIM;
    const float* h1p = hidden + (size_t)r1 * HDIM;

    double acc0[LTAGS], acc1[LTAGS];
    #pragma unroll
    for (int l = 0; l < LTAGS; ++l) { acc0[l] = 0.0; acc1[l] = 0.0; }

    #pragma unroll 2
    for (int i = 0; i < 24; ++i) {
        const int off = i * 32 + sub * 4;
        const float4 h0 = *(const float4*)(h0p + off);
        const float4 h1 = *(const float4*)(h1p + off);
        #pragma unroll
        for (int l = 0; l < LTAGS; ++l) {
            const float4 w = *(const float4*)&sW[l * HDIM + off];
            float d0 = h0.x * w.x;
            d0 = fmaf(h0.y, w.y, d0); d0 = fmaf(h0.z, w.z, d0); d0 = fmaf(h0.w, w.w, d0);
            float d1 = h1.x * w.x;
            d1 = fmaf(h1.y, w.y, d1); d1 = fmaf(h1.z, w.z, d1); d1 = fmaf(h1.w, w.w, d1);
            acc0[l] += (double)d0;
            acc1[l] += (double)d1;
        }
    }
    #pragma unroll
    for (int l = 0; l < LTAGS; ++l) {
        double v0 = acc0[l], v1 = acc1[l];
        #pragma unroll
        for (int off = 4; off > 0; off >>= 1) {
            v0 += __shfl_down(v0, off);
            v1 += __shfl_down(v1, off);
        }
        acc0[l] = v0; acc1[l] = v1;
    }
    if (sub == 0) {
        #pragma unroll
        for (int l = 0; l < LTAGS; ++l) {
            logitsD[(size_t)r0 * LTAGS + l] = acc0[l] + (double)sb[l];
            logitsD[(size_t)r1 * LTAGS + l] = acc1[l] + (double)sb[l];
        }
    }
}

// ---------------------------------------------------------------------------
// Kernel B1 (chunk): 232 blocks x 256 threads.
//   blocks [0,144):   Viterbi chunk-matrix rows (b,c,i), f64 max-plus, 8 steps
//   blocks [144,216): alpha chunk-matrix rows (b,c,i), f32 log-plus, 16 steps
//   blocks [216,232): numerator, one wave per batch
// Inner loops k-outer/j-inner with padded 16B-aligned T rows -> vector LDS
// reads; per-j op ORDER identical to round 3 (bit-exact).
// ---------------------------------------------------------------------------
__global__ __launch_bounds__(256) void chunk_kernel(
    const float* __restrict__ trans, const int* __restrict__ labels,
    const int* __restrict__ att, const double* __restrict__ logitsD,
    double* __restrict__ wsVM, float* __restrict__ wsAM,
    double* __restrict__ wsNum, float* __restrict__ out)
{
    __shared__ __align__(16) double sT64[90];   // padded k*10+j
    __shared__ __align__(16) float  sE32[108];  // padded k*12+j
    const int tid = threadIdx.x;
    if (tid < 81) {
        const int k = tid / 9, j = tid - 9 * k;
        float tv = trans[tid];
        sT64[k * 10 + j] = (double)tv;
        sE32[k * 12 + j] = __expf(tv);
    }
    if (blockIdx.x == 0 && tid == 0) out[0] = 0.f;   // init for atomic loss
    __syncthreads();

    const int blk = blockIdx.x;
    if (blk < 144) {
        // ---- Viterbi chunk rows ----
        const int gid = blk * 256 + tid;
        const int b   = gid / 576;
        const int rem = gid - b * 576;
        const int c   = rem / 9;
        const int i   = rem - c * 9;

        double M[LTAGS];
        #pragma unroll
        for (int j = 0; j < LTAGS; ++j) M[j] = (i == j) ? 0.0 : -1e300;

        const double* lrow = logitsD + ((size_t)b * TLEN + (c * 8 + 1)) * LTAGS;
        const int* lab = labels + b * TLEN;
        const int* am  = att + b * TLEN;
        const int t0 = c * 8 + 1;

        double lg[LTAGS], lgN[LTAGS];
        #pragma unroll
        for (int j = 0; j < LTAGS; ++j) lg[j] = lrow[j];
        bool mk = (am[t0] != 0) && (lab[t0] != -100);

        for (int s = 0; s < 8; ++s) {
            bool mkN = false;
            const int tn = t0 + s + 1;
            if (s < 7 && tn <= TLEN - 1) {
                const double* ln = lrow + (s + 1) * LTAGS;
                #pragma unroll
                for (int j = 0; j < LTAGS; ++j) lgN[j] = ln[j];
                mkN = (am[tn] != 0) && (lab[tn] != -100);
            }
            double nw[LTAGS];
            #pragma unroll
            for (int k = 0; k < LTAGS; ++k) {
                const double2* r = (const double2*)&sT64[k * 10];
                const double2 r01 = r[0], r23 = r[1], r45 = r[2], r67 = r[3];
                const double r8 = sT64[k * 10 + 8];
                const double mk64 = M[k];
                if (k == 0) {
                    nw[0] = mk64 + r01.x; nw[1] = mk64 + r01.y;
                    nw[2] = mk64 + r23.x; nw[3] = mk64 + r23.y;
                    nw[4] = mk64 + r45.x; nw[5] = mk64 + r45.y;
                    nw[6] = mk64 + r67.x; nw[7] = mk64 + r67.y;
                    nw[8] = mk64 + r8;
                } else {
                    nw[0] = fmax(nw[0], mk64 + r01.x); nw[1] = fmax(nw[1], mk64 + r01.y);
                    nw[2] = fmax(nw[2], mk64 + r23.x); nw[3] = fmax(nw[3], mk64 + r23.y);
                    nw[4] = fmax(nw[4], mk64 + r45.x); nw[5] = fmax(nw[5], mk64 + r45.y);
                    nw[6] = fmax(nw[6], mk64 + r67.x); nw[7] = fmax(nw[7], mk64 + r67.y);
                    nw[8] = fmax(nw[8], mk64 + r8);
                }
            }
            #pragma unroll
            for (int j = 0; j < LTAGS; ++j) {
                M[j] = mk ? (nw[j] + lg[j]) : M[j];
                lg[j] = lgN[j];
            }
            mk = mkN;
        }
        double* dst = wsVM + (((size_t)b * 64 + c) * LTAGS + i) * LTAGS;
        #pragma unroll
        for (int j = 0; j < LTAGS; ++j) dst[j] = M[j];
    } else if (blk < 216) {
        // ---- alpha chunk rows ----
        const int gid = (blk - 144) * 256 + tid;
        const int b   = gid / 288;
        const int rem = gid - b * 288;
        const int c   = rem / 9;
        const int i   = rem - c * 9;

        float M[LTAGS];
        #pragma unroll
        for (int j = 0; j < LTAGS; ++j) M[j] = (i == j) ? 0.f : -1e30f;

        const double* lrow = logitsD + ((size_t)b * TLEN + (c * 16 + 1)) * LTAGS;
        const int* lab = labels + b * TLEN;
        const int* am  = att + b * TLEN;
        const int t0 = c * 16 + 1;

        float lg[LTAGS], lgN[LTAGS];
        #pragma unroll
        for (int j = 0; j < LTAGS; ++j) lg[j] = (float)lrow[j];
        bool mk = (am[t0] != 0) && (lab[t0] != -100);

        for (int s = 0; s < 16; ++s) {
            bool mkN = false;
            const int tn = t0 + s + 1;
            if (s < 15 && tn <= TLEN - 1) {
                const double* ln = lrow + (s + 1) * LTAGS;
                #pragma unroll
                for (int j = 0; j < LTAGS; ++j) lgN[j] = (float)ln[j];
                mkN = (am[tn] != 0) && (lab[tn] != -100);
            }
            float m = M[0];
            #pragma unroll
            for (int k = 1; k < LTAGS; ++k) m = fmaxf(m, M[k]);
            float P[LTAGS];
            #pragma unroll
            for (int k = 0; k < LTAGS; ++k) P[k] = __expf(M[k] - m);
            float sa[LTAGS];
            #pragma unroll
            for (int k = 0; k < LTAGS; ++k) {
                const float4* r = (const float4*)&sE32[k * 12];
                const float4 f03 = r[0], f47 = r[1];
                const float f8 = sE32[k * 12 + 8];
                const float pk = P[k];
                if (k == 0) {
                    sa[0] = pk * f03.x; sa[1] = pk * f03.y; sa[2] = pk * f03.z; sa[3] = pk * f03.w;
                    sa[4] = pk * f47.x; sa[5] = pk * f47.y; sa[6] = pk * f47.z; sa[7] = pk * f47.w;
                    sa[8] = pk * f8;
                } else {
                    sa[0] = fmaf(pk, f03.x, sa[0]); sa[1] = fmaf(pk, f03.y, sa[1]);
                    sa[2] = fmaf(pk, f03.z, sa[2]); sa[3] = fmaf(pk, f03.w, sa[3]);
                    sa[4] = fmaf(pk, f47.x, sa[4]); sa[5] = fmaf(pk, f47.y, sa[5]);
                    sa[6] = fmaf(pk, f47.z, sa[6]); sa[7] = fmaf(pk, f47.w, sa[7]);
                    sa[8] = fmaf(pk, f8,    sa[8]);
                }
            }
            #pragma unroll
            for (int j = 0; j < LTAGS; ++j) {
                float nwj = m + __logf(sa[j]) + lg[j];
                M[j] = mk ? nwj : M[j];
                lg[j] = lgN[j];
            }
            mk = mkN;
        }
        float* dst = wsAM + (((size_t)b * 32 + c) * LTAGS + i) * LTAGS;
        #pragma unroll
        for (int j = 0; j < LTAGS; ++j) dst[j] = M[j];
    } else {
        // ---- numerator: one wave per batch ----
        const int bb   = (blk - 216) * 4 + (tid >> 6);
        const int lane = tid & 63;
        const int* lab = labels + bb * TLEN;
        const int* am  = att + bb * TLEN;
        const double* lrowb = logitsD + (size_t)bb * TLEN * LTAGS;
        double part = 0.0;
        #pragma unroll
        for (int k = 0; k < 8; ++k) {
            const int t = lane + k * 64;
            int lv = lab[t], av = am[t];
            bool mkc = (av != 0) && (lv != -100);
            int tg = (lv == -100) ? 0 : lv;
            if (mkc) part += lrowb[(size_t)t * LTAGS + tg];
            if (t < TLEN - 1) {
                int lv2 = lab[t + 1], av2 = am[t + 1];
                bool mk2 = (av2 != 0) && (lv2 != -100);
                int tg2 = (lv2 == -100) ? 0 : lv2;
                if (mk2) part += sT64[tg * 10 + tg2];
            }
        }
        #pragma unroll
        for (int off = 32; off > 0; off >>= 1) part += __shfl_down(part, off);
        if (lane == 0) wsNum[bb] = part;
    }
}

// ---------------------------------------------------------------------------
// Kernel B2 (crf2): per-batch block, 128 threads.  Chunk mats staged to LDS;
// wave0: boundary scan (tree-fmax, bit-exact) + replay + shfl-suffix backtrace
// wave1: log-plus boundary scan -> denominator.  Loss via one f32 atomicAdd.
// ---------------------------------------------------------------------------
__global__ __launch_bounds__(128) void crf2_kernel(
    const float* __restrict__ trans, const int* __restrict__ labels,
    const int* __restrict__ att, const double* __restrict__ logitsD,
    const double* __restrict__ wsVM, const float* __restrict__ wsAM,
    const double* __restrict__ wsNum, float* __restrict__ out)
{
    __shared__ __align__(16) double sVM[64 * 81];     // 41472 B
    __shared__ __align__(16) float  sAM[32 * 81];     // 10368 B
    __shared__ double sVstart[65 * LTAGS];            // 4680 B
    __shared__ unsigned long long sBPp[513];          // 4104 B
    __shared__ int sTagB[65];
    __shared__ __align__(16) double sT64[90];         // padded k*10+j
    __shared__ unsigned char sMk[513];
    __shared__ double sDen;
    __shared__ int sLast;

    const int b = blockIdx.x, tid = threadIdx.x;
    const int wave = tid >> 6, lane = tid & 63;
    const unsigned long long IDMAP = 0x876543210ull;

    // ---- stage chunk matrices + masks into LDS (coalesced) ----
    const double2* gVM = (const double2*)(wsVM + (size_t)b * 64 * 81);
    double2* sVM2 = (double2*)sVM;
    for (int i = tid; i < 2592; i += 128) sVM2[i] = gVM[i];
    const float4* gAM = (const float4*)(wsAM + (size_t)b * 32 * 81);
    float4* sAM4 = (float4*)sAM;
    for (int i = tid; i < 648; i += 128) sAM4[i] = gAM[i];

    const int* lab = labels + b * TLEN;
    const int* am  = att + b * TLEN;
    for (int t = tid; t < TLEN; t += 128) {
        int lv = lab[t], av = am[t];
        sMk[t] = (av != 0 && lv != -100) ? 1 : 0;
    }
    if (tid == 0) sMk[TLEN] = 0;
    if (tid < 81) {
        const int k = tid / 9, j = tid - 9 * k;
        sT64[k * 10 + j] = (double)trans[tid];
    }
    __syncthreads();

    if (wave == 0) {
        // ---- Viterbi boundary scan over 64 chunk matrices (LDS) ----
        const int j = (lane < LTAGS) ? lane : (LTAGS - 1);
        double v = logitsD[(size_t)b * TLEN * LTAGS + j];
        double Mc[LTAGS], Mn[LTAGS];
        #pragma unroll
        for (int i = 0; i < LTAGS; ++i) Mc[i] = sVM[i * LTAGS + j];
        for (int c = 0; c < 64; ++c) {
            if (c < 63) {
                #pragma unroll
                for (int i = 0; i < LTAGS; ++i) Mn[i] = sVM[(c + 1) * 81 + i * LTAGS + j];
            }
            if (lane < LTAGS) sVstart[c * LTAGS + j] = v;
            double g[LTAGS];
            #pragma unroll
            for (int i = 0; i < LTAGS; ++i) g[i] = __shfl(v, i);
            double a0 = g[0] + Mc[0], a1 = g[1] + Mc[1], a2 = g[2] + Mc[2];
            double a3 = g[3] + Mc[3], a4 = g[4] + Mc[4], a5 = g[5] + Mc[5];
            double a6 = g[6] + Mc[6], a7 = g[7] + Mc[7], a8 = g[8] + Mc[8];
            // tree fmax: exact (fmax associative/commutative, no NaNs)
            double t01 = fmax(a0, a1), t23 = fmax(a2, a3);
            double t45 = fmax(a4, a5), t67 = fmax(a6, a7);
            v = fmax(fmax(fmax(t01, t23), fmax(t45, t67)), a8);
            if (c < 63) {
                #pragma unroll
                for (int i = 0; i < LTAGS; ++i) Mc[i] = Mn[i];
            }
        }
        if (lane < LTAGS) sVstart[64 * LTAGS + j] = v;
        double g[LTAGS];
        #pragma unroll
        for (int i = 0; i < LTAGS; ++i) g[i] = __shfl(v, i);
        if (lane == 0) {
            int bi = 0; double bv = g[0];
            #pragma unroll
            for (int i = 1; i < LTAGS; ++i) if (g[i] > bv) { bv = g[i]; bi = i; }
            sLast = bi;
        }
    } else {
        // ---- alpha boundary scan over 32 chunk matrices (LDS) ----
        const int j = (lane < LTAGS) ? lane : (LTAGS - 1);
        float v = (float)logitsD[(size_t)b * TLEN * LTAGS + j];
        float Mc[LTAGS], Mn[LTAGS];
        #pragma unroll
        for (int i = 0; i < LTAGS; ++i) Mc[i] = sAM[i * LTAGS + j];
        for (int c = 0; c < 32; ++c) {
            if (c < 31) {
                #pragma unroll
                for (int i = 0; i < LTAGS; ++i) Mn[i] = sAM[(c + 1) * 81 + i * LTAGS + j];
            }
            float g[LTAGS];
            #pragma unroll
            for (int i = 0; i < LTAGS; ++i) g[i] = __shfl(v, i);
            float a[LTAGS];
            #pragma unroll
            for (int i = 0; i < LTAGS; ++i) a[i] = g[i] + Mc[i];
            // tree fmaxf (exact); f32 add order below preserved
            float t01 = fmaxf(a[0], a[1]), t23 = fmaxf(a[2], a[3]);
            float t45 = fmaxf(a[4], a[5]), t67 = fmaxf(a[6], a[7]);
            float m = fmaxf(fmaxf(fmaxf(t01, t23), fmaxf(t45, t67)), a[8]);
            float sacc = 0.f;
            #pragma unroll
            for (int i = 0; i < LTAGS; ++i) sacc += __expf(a[i] - m);
            v = m + __logf(sacc);
            if (c < 31) {
                #pragma unroll
                for (int i = 0; i < LTAGS; ++i) Mc[i] = Mn[i];
            }
        }
        float g[LTAGS];
        #pragma unroll
        for (int i = 0; i < LTAGS; ++i) g[i] = __shfl(v, i);
        if (lane == 0) {
            float m = g[0];
            #pragma unroll
            for (int i = 1; i < LTAGS; ++i) m = fmaxf(m, g[i]);
            float sacc = 0.f;
            #pragma unroll
            for (int i = 0; i < LTAGS; ++i) sacc += __expf(g[i] - m);
            sDen = (double)(m + __logf(sacc));
        }
    }
    __syncthreads();

    // ---- replay: backpointers + per-chunk composed maps (threads 0..63) ----
    unsigned long long S = IDMAP;
    if (tid < 64) {
        const int c = tid;
        double v[LTAGS];
        #pragma unroll
        for (int j = 0; j < LTAGS; ++j) v[j] = sVstart[c * LTAGS + j];
        const double* lrow = logitsD + ((size_t)b * TLEN + (c * 8 + 1)) * LTAGS;
        double lg[LTAGS], lgN[LTAGS];
        #pragma unroll
        for (int j = 0; j < LTAGS; ++j) lg[j] = lrow[j];

        for (int s = 0; s < 8; ++s) {
            const int t = c * 8 + 1 + s;
            if (s < 7 && t + 1 <= TLEN - 1) {
                const double* ln = lrow + (s + 1) * LTAGS;
                #pragma unroll
                for (int j = 0; j < LTAGS; ++j) lgN[j] = ln[j];
            }
            const bool mk = (sMk[t] != 0);
            double bst[LTAGS];
            int bi[LTAGS];
            // k-outer with vector T reads; per-j compare sequence identical
            #pragma unroll
            for (int k = 0; k < LTAGS; ++k) {
                const double2* r = (const double2*)&sT64[k * 10];
                const double2 r01 = r[0], r23 = r[1], r45 = r[2], r67 = r[3];
                const double r8 = sT64[k * 10 + 8];
                const double vk = v[k];
                double cnd[LTAGS];
                cnd[0] = vk + r01.x; cnd[1] = vk + r01.y;
                cnd[2] = vk + r23.x; cnd[3] = vk + r23.y;
                cnd[4] = vk + r45.x; cnd[5] = vk + r45.y;
                cnd[6] = vk + r67.x; cnd[7] = vk + r67.y;
                cnd[8] = vk + r8;
                if (k == 0) {
                    #pragma unroll
                    for (int j = 0; j < LTAGS; ++j) { bst[j] = cnd[j]; bi[j] = 0; }
                } else {
                    #pragma unroll
                    for (int j = 0; j < LTAGS; ++j) {
                        bool gt = cnd[j] > bst[j];     // strict >: ties keep lowest k
                        bst[j] = gt ? cnd[j] : bst[j];
                        bi[j]  = gt ? k : bi[j];
                    }
                }
            }
            unsigned long long pk = 0;
            #pragma unroll
            for (int j = 0; j < LTAGS; ++j)
                pk |= ((unsigned long long)bi[j]) << (4 * j);
            pk = mk ? pk : IDMAP;
            sBPp[t] = pk;
            #pragma unroll
            for (int j = 0; j < LTAGS; ++j) {
                v[j] = mk ? (bst[j] + lg[j]) : v[j];
                lg[j] = lgN[j];
            }
        }
        // compose chunk backtrace map
        unsigned long long G = IDMAP;
        for (int s = 7; s >= 0; --s) {
            const unsigned long long bp = sBPp[c * 8 + 1 + s];
            unsigned long long ng = 0;
            #pragma unroll
            for (int j = 0; j < LTAGS; ++j) {
                int gj = (int)((G >> (4 * j)) & 15);
                int f  = (int)((bp >> (4 * gj)) & 15);
                ng |= ((unsigned long long)f) << (4 * j);
            }
            G = ng;
        }
        S = G;
    }

    // ---- suffix composition scan via shfl: S_c = F_c o ... o F_63 ----
    #pragma unroll
    for (int d = 1; d < 64; d <<= 1) {
        unsigned long long Sn = __shfl_down(S, d);
        if (wave == 0 && lane + d < 64) {
            unsigned long long R = 0;
            #pragma unroll
            for (int x = 0; x < LTAGS; ++x) {
                int y = (int)((Sn >> (4 * x)) & 15);
                int z = (int)((S >> (4 * y)) & 15);
                R |= ((unsigned long long)z) << (4 * x);
            }
            S = R;
        }
    }
    if (tid < 64) {
        const int lt = sLast;
        sTagB[tid] = (int)((S >> (4 * lt)) & 15);
        if (tid == 0) sTagB[64] = lt;
    }
    __syncthreads();

    // ---- chunk-parallel expansion -> predictions ----
    if (tid < 64) {
        const int c = tid;
        int cur = sTagB[c + 1];
        float* po = out + 1 + b * TLEN;
        for (int s = 8; s >= 1; --s) {
            const int t = c * 8 + s;
            if (t < TLEN) {
                int nxt = (int)((sBPp[t] >> (4 * cur)) & 15);
                po[t] = sMk[t - 1] ? (float)nxt : -100.f;
                cur = nxt;
            }
        }
    }
    if (tid == 0) {
        out[1 + b * TLEN] = -100.f;
        atomicAdd(out, (float)(sDen - wsNum[b]));   // loss (den - num), f32 atomic
    }
}

extern "C" void kernel_launch(void* const* d_in, const int* in_sizes, int n_in,
                              void* d_out, int out_size, void* d_ws, size_t ws_size,
                              hipStream_t stream)
{
    const float* hidden = (const float*)d_in[0];
    const float* W      = (const float*)d_in[1];
    const float* bvec   = (const float*)d_in[2];
    const float* trans  = (const float*)d_in[3];
    const int*   labels = (const int*)d_in[4];
    const int*   att    = (const int*)d_in[5];
    float* out = (float*)d_out;

    char* ws = (char*)d_ws;
    double* logitsD = (double*)(ws + WS_LOGD);
    double* wsVM    = (double*)(ws + WS_VM);
    float*  wsAM    = (float*)(ws + WS_AM);
    double* wsNum   = (double*)(ws + WS_NUM);

    logits_kernel<<<512, 256, 0, stream>>>(hidden, W, bvec, logitsD);
    chunk_kernel<<<232, 256, 0, stream>>>(trans, labels, att, logitsD,
                                          wsVM, wsAM, wsNum, out);
    crf2_kernel<<<BATCH, 128, 0, stream>>>(trans, labels, att, logitsD,
                                           wsVM, wsAM, wsNum, out);
}